// Round 6
// baseline (241.847 us; speedup 1.0000x reference)
//
#include <hip/hip_runtime.h>
#include <hip/hip_bf16.h>
#include <math.h>

typedef __bf16 bf16_t;
typedef __bf16 bf16x8 __attribute__((ext_vector_type(8)));
typedef __bf16 bf16x4 __attribute__((ext_vector_type(4)));
typedef short short4v __attribute__((ext_vector_type(4)));
typedef float f32x4 __attribute__((ext_vector_type(4)));

__device__ __forceinline__ f32x4 mfma_k32(bf16x8 a, bf16x8 b, f32x4 c) {
    return __builtin_amdgcn_mfma_f32_16x16x32_bf16(a, b, c, 0, 0, 0);
}

__device__ __forceinline__ f32x4 mfma_k16(bf16x4 a, bf16x4 b, f32x4 c) {
#if __has_builtin(__builtin_amdgcn_mfma_f32_16x16x16_bf16)
    return __builtin_amdgcn_mfma_f32_16x16x16_bf16(a, b, c, 0, 0, 0);
#elif __has_builtin(__builtin_amdgcn_mfma_f32_16x16x16bf16_1k)
    short4v as, bs;
    __builtin_memcpy(&as, &a, 8);
    __builtin_memcpy(&bs, &b, 8);
    return __builtin_amdgcn_mfma_f32_16x16x16bf16_1k(as, bs, c, 0, 0, 0);
#else
    f32x4 d = c;
    asm volatile("v_mfma_f32_16x16x16_bf16 %0, %1, %2, %0" : "+v"(d) : "v"(a), "v"(b));
    return d;
#endif
}

// raw v_exp_f32 (exp2): avoid OCML guard code around exp2f
__device__ __forceinline__ float fast_exp2(float x) {
#if __has_builtin(__builtin_amdgcn_exp2f)
    return __builtin_amdgcn_exp2f(x);
#else
    float r;
    asm("v_exp_f32 %0, %1" : "=v"(r) : "v"(x));
    return r;
#endif
}

// async global->LDS, 16B/lane; LDS dest = wave-uniform base + lane*16
__device__ __forceinline__ void async16(const bf16_t* g, __bf16* l) {
    __builtin_amdgcn_global_load_lds(
        (const __attribute__((address_space(1))) void*)g,
        (__attribute__((address_space(3))) void*)l, 16, 0, 0);
}

// XOR-swizzle: 16B chunks within each 64-col group, keyed by row&7 (global-side)
__device__ __forceinline__ int swz_col(int col, int row) {
    return (col & ~63) | ((((col >> 3) & 7) ^ (row & 7)) << 3) | (col & 7);
}

__device__ __forceinline__ bf16x8 cvt8(float4 a, float4 b) {
    bf16x8 w;
    w[0]=(__bf16)a.x; w[1]=(__bf16)a.y; w[2]=(__bf16)a.z; w[3]=(__bf16)a.w;
    w[4]=(__bf16)b.x; w[5]=(__bf16)b.y; w[6]=(__bf16)b.z; w[7]=(__bf16)b.w;
    return w;
}

// ---------------------------------------------------------------------------
// fp32 -> bf16 swizzled convert, W only (x conversion fused into proj).
// ---------------------------------------------------------------------------
__global__ __launch_bounds__(256) void cvt_W(const float* __restrict__ Wq,
                                             const float* __restrict__ Wk,
                                             const float* __restrict__ Wv,
                                             const float* __restrict__ Wo,
                                             bf16_t* __restrict__ Wc) {
    const int b2 = blockIdx.x;
    const int m = b2 >> 7;                   // which W
    const float* src = m == 0 ? Wq : m == 1 ? Wk : m == 2 ? Wv : Wo;
    const float sc = (m == 0) ? 0.125f * 1.44269504088896f : 1.0f;
    size_t i = ((size_t)(b2 & 127) * 256 + threadIdx.x) * 8;
    int row = (int)(i >> 9), col = (int)(i & 511);
    float4 a0 = *(const float4*)(src + i), a1 = *(const float4*)(src + i + 4);
    bf16x8 o;
    o[0]=(__bf16)(a0.x*sc); o[1]=(__bf16)(a0.y*sc); o[2]=(__bf16)(a0.z*sc); o[3]=(__bf16)(a0.w*sc);
    o[4]=(__bf16)(a1.x*sc); o[5]=(__bf16)(a1.y*sc); o[6]=(__bf16)(a1.z*sc); o[7]=(__bf16)(a1.w*sc);
    *(bf16x8*)(Wc + (size_t)m * 262144 + (size_t)row * 512 + swz_col(col, row)) = o;
}

// ---------------------------------------------------------------------------
// 128x128-tile NT GEMM (m97 structure), per-operand staging (proven R4/R5):
//   AF32/BF32 = 1: fp32 operand; reg-load 32B/lane, cvt, Latin-square-swizzled
//     ds_write_b128. 0: pre-swizzled bf16; global_load_lds direct.
// ---------------------------------------------------------------------------
template<int MODE, int AF32, int BF32>
__device__ __forceinline__ void gemm128_body(const bf16_t* __restrict__ Ab,
                                             const float* __restrict__ Af,
                                             const bf16_t* __restrict__ Bb,
                                             const float* __restrict__ Bf,
                                             void* __restrict__ outp,
                                             int m0, int n0) {
    __shared__ __bf16 Asm[128 * 64];
    __shared__ __bf16 Bsm[128 * 64];
    const int tid  = threadIdx.x;
    const int wave = tid >> 6;
    const int lane = tid & 63;
    const int quad = lane >> 4;
    const int l16  = lane & 15;
    const int swz  = l16 & 7;
    const int r8 = lane >> 3;
    const int c8 = (lane & 7) * 8;
    const int mrow0 = (wave & 1) * 64;
    const int ncol0 = (wave >> 1) * 64;

    f32x4 acc[4][4];
    for (int i = 0; i < 4; ++i)
        for (int j = 0; j < 4; ++j) acc[i][j] = (f32x4){0.f, 0.f, 0.f, 0.f};

    for (int kt = 0; kt < 512; kt += 64) {
        __syncthreads();
        for (int j = 0; j < 4; ++j) {
            const int rl = wave * 32 + j * 8 + r8;
            if (AF32) {
                const float* s = Af + (size_t)(m0 + rl) * 512 + kt + c8;
                float4 v0 = *(const float4*)s, v1 = *(const float4*)(s + 4);
                *(bf16x8*)&Asm[rl * 64 + (((lane & 7) ^ r8) << 3)] = cvt8(v0, v1);
            } else {
                async16(Ab + (size_t)(m0 + rl) * 512 + kt + c8,
                        &Asm[(wave * 32 + j * 8) * 64]);
            }
            if (BF32) {
                const float* s = Bf + (size_t)(n0 + rl) * 512 + kt + c8;
                float4 v0 = *(const float4*)s, v1 = *(const float4*)(s + 4);
                *(bf16x8*)&Bsm[rl * 64 + (((lane & 7) ^ r8) << 3)] = cvt8(v0, v1);
            } else {
                async16(Bb + (size_t)(n0 + rl) * 512 + kt + c8,
                        &Bsm[(wave * 32 + j * 8) * 64]);
            }
        }
        __syncthreads();

        for (int ks = 0; ks < 2; ++ks) {
            bf16x8 af[4];
            for (int mt = 0; mt < 4; ++mt)
                af[mt] = *(const bf16x8*)&Asm[(mrow0 + mt * 16 + l16) * 64 + ((ks * 4 + quad) ^ swz) * 8];
            for (int nt = 0; nt < 4; ++nt) {
                bf16x8 bf = *(const bf16x8*)&Bsm[(ncol0 + nt * 16 + l16) * 64 + ((ks * 4 + quad) ^ swz) * 8];
                for (int mt = 0; mt < 4; ++mt)
                    acc[mt][nt] = mfma_k32(af[mt], bf, acc[mt][nt]);
            }
        }
    }

    if (MODE == 0) {
        bf16_t* out = (bf16_t*)outp;
        for (int nt = 0; nt < 4; ++nt) {
            int e = n0 + ncol0 + nt * 16 + l16;
            int h = e >> 6, el = e & 63;
            for (int mt = 0; mt < 4; ++mt)
                for (int r = 0; r < 4; ++r) {
                    int row = m0 + mrow0 + mt * 16 + quad * 4 + r;   // b*4096+s
                    int b = row >> 12, s = row & 4095;
                    int elp = (((el >> 3) ^ (row & 7)) << 3) | (el & 7);
                    out[(((size_t)(b * 8 + h)) * 4096 + s) * 64 + elp] = (bf16_t)acc[mt][nt][r];
                }
        }
    } else {
        bf16_t* out = (bf16_t*)outp;
        for (int nt = 0; nt < 4; ++nt) {
            int s_g = n0 + ncol0 + nt * 16 + l16;
            int b = s_g >> 12;
            int sbase = (s_g & 4095) & ~63;
            int f = 16 * ((l16 >> 2) & 3) + 4 * nt + (l16 & 3);
            for (int mt = 0; mt < 4; ++mt)
                for (int r = 0; r < 4; ++r) {
                    int e_g = m0 + mrow0 + mt * 16 + quad * 4 + r;
                    int h = e_g >> 6, el = e_g & 63;
                    int col = sbase | ((((f >> 3) ^ (e_g & 7)) & 7) << 3) | (f & 7);
                    out[(((size_t)(b * 8 + h)) * 64 + el) * 4096 + col] = (bf16_t)acc[mt][nt][r];
                }
        }
    }
}

// grid (256,1,3); XCD-sibling swizzle: same-A-stripe blocks (4 y's) get ids
// 8 apart -> same XCD round-robin -> stripe L2-served.
__global__ __launch_bounds__(256) void proj_fused(const float* __restrict__ q,
                                                  const float* __restrict__ k,
                                                  const float* __restrict__ v,
                                                  const bf16_t* __restrict__ Wc,
                                                  bf16_t* __restrict__ qh,
                                                  bf16_t* __restrict__ kh,
                                                  bf16_t* __restrict__ vh) {
    const int f = blockIdx.x;
    const int y = (f >> 3) & 3;
    const int x = (f & 7) | ((f >> 5) << 3);
    const int z = blockIdx.z;
    const bf16_t* W = Wc + (size_t)z * 262144;
    if (z == 0)
        gemm128_body<0, 1, 0>(nullptr, q, W, nullptr, qh, x * 128, y * 128);
    else if (z == 1)
        gemm128_body<0, 1, 0>(nullptr, k, W, nullptr, kh, x * 128, y * 128);
    else
        gemm128_body<1, 0, 1>(W, nullptr, nullptr, v, vh, y * 128, x * 128);
}

// ---------------------------------------------------------------------------
// Final GEMM with fused z-combine + softmax normalization (proven R4),
// XCD-sibling grid swizzle.
// ---------------------------------------------------------------------------
__global__ __launch_bounds__(256) void gemm_final(const bf16_t* __restrict__ Op,
                                                  const float* __restrict__ Lp,
                                                  const bf16_t* __restrict__ B,
                                                  float* __restrict__ out) {
    __shared__ __bf16 Asm[128 * 64];
    __shared__ __bf16 Bsm[128 * 64];
    const int fb = blockIdx.x;
    const int m0 = ((fb & 7) | ((fb >> 5) << 3)) * 128;
    const int n0 = ((fb >> 3) & 3) * 128;
    const int tid  = threadIdx.x;
    const int wave = tid >> 6;
    const int lane = tid & 63;
    const int quad = lane >> 4;
    const int l16  = lane & 15;
    const int swz  = l16 & 7;
    const int r8 = lane >> 3;
    const int c8 = (lane & 7) * 8;
    const int mrow0 = (wave & 1) * 64;
    const int ncol0 = (wave >> 1) * 64;

    f32x4 acc[4][4];
    for (int i = 0; i < 4; ++i)
        for (int j = 0; j < 4; ++j) acc[i][j] = (f32x4){0.f, 0.f, 0.f, 0.f};

    for (int kt = 0; kt < 512; kt += 64) {
        const int h = kt >> 6;
        __syncthreads();
        for (int j = 0; j < 4; ++j)
            async16(B + (size_t)(n0 + wave * 32 + j * 8 + r8) * 512 + kt + c8,
                    &Bsm[(wave * 32 + j * 8) * 64]);
        for (int j = 0; j < 4; ++j) {
            const int rl  = wave * 32 + j * 8 + r8;
            const int row = m0 + rl;                 // b*4096 + s
            const int b   = row >> 12, sp = row & 4095;
            const size_t lidx = (size_t)(b * 8 + h) * 4096 + sp;
            bf16x8 a0 = *(const bf16x8*)(Op + lidx * 64 + c8);
            bf16x8 a1 = *(const bf16x8*)(Op + 4194304 + lidx * 64 + c8);
            float inv = 1.0f / (Lp[lidx] + Lp[65536 + lidx]);
            bf16x8 w;
            for (int i = 0; i < 8; ++i)
                w[i] = (bf16_t)(((float)a0[i] + (float)a1[i]) * inv);
            *(bf16x8*)&Asm[rl * 64 + (((lane & 7) ^ r8) << 3)] = w;
        }
        __syncthreads();

        for (int ks = 0; ks < 2; ++ks) {
            bf16x8 af[4];
            for (int mt = 0; mt < 4; ++mt)
                af[mt] = *(const bf16x8*)&Asm[(mrow0 + mt * 16 + l16) * 64 + ((ks * 4 + quad) ^ swz) * 8];
            for (int nt = 0; nt < 4; ++nt) {
                bf16x8 bf = *(const bf16x8*)&Bsm[(ncol0 + nt * 16 + l16) * 64 + ((ks * 4 + quad) ^ swz) * 8];
                for (int mt = 0; mt < 4; ++mt)
                    acc[mt][nt] = mfma_k32(af[mt], bf, acc[mt][nt]);
            }
        }
    }

    for (int nt = 0; nt < 4; ++nt) {
        int n = n0 + ncol0 + nt * 16 + l16;
        for (int mt = 0; mt < 4; ++mt)
            for (int r = 0; r < 4; ++r) {
                int row = m0 + mrow0 + mt * 16 + quad * 4 + r;
                out[(size_t)row * 512 + n] = acc[mt][nt][r];
            }
    }
}

// ---------------------------------------------------------------------------
// Causal flash attention v9: QBLK 64 -> 128 (8 waves, 512 threads, 512
// blocks = 2/CU). Each 32KB K/V panel now feeds 2x the queries: block-steps
// per bh drop 1072 -> 528, halving per-step load-issue + barrier-drain
// overhead per unit MFMA. The per-wave inner loop (16 k32 QK + 32 k16 PV +
// 32 exp2) is byte-identical to v7 (62.6us proven); only the wave->tile
// decomposition changes: wl = wave&3 (query quarter), g2 = wave>>2 (K
// parity). Osc [128][65] f32 overlay; global Opart/Lp layouts unchanged.
// ---------------------------------------------------------------------------
__global__ __launch_bounds__(512, 4) void attn_kernel(const bf16_t* __restrict__ qh,
                                                      const bf16_t* __restrict__ kh,
                                                      const bf16_t* __restrict__ vh,
                                                      bf16_t* __restrict__ Opart,
                                                      float* __restrict__ Lpart) {
    __shared__ __bf16 SM[16896];            // 33 KB: K[128][64] + V[128][64]
    __bf16* KSM = &SM[0];
    __bf16* VSM = &SM[8192];
    float* Osc = (float*)SM;                // 33.3 KB leg-end scratch [q][65]
    float* Lsc = (float*)&SM[16640];        // 512 B lsum scratch [q] (byte 33280)

    const int id   = blockIdx.x;
    const int bh   = ((id & 7) << 1) | ((id >> 3) & 1);   // XCD-grouped, 2 bh/XCD
    const int pair = (id >> 4) & 15;
    const int z    = (id >> 8) & 1;

    const int tid  = threadIdx.x;
    const int wave = tid >> 6;
    const int g2   = wave >> 2;             // K-panel parity within step
    const int wl   = wave & 3;              // query quarter
    const int lane = tid & 63;
    const int quad = lane >> 4;
    const int l16  = lane & 15;
    const int swz  = l16 & 7;
    const size_t base = (size_t)bh * 4096 * 64;
    const int r8 = lane >> 3;
    const int c8 = (lane & 7) * 8;

    bf16_t* Op = Opart + (size_t)z * 4194304;
    float*  Lp = Lpart + z * 65536;

    for (int leg = 0; leg < 2; ++leg) {
        const int qt2 = leg ? (31 - pair) : pair;
        const int q0 = qt2 * 128;

        bf16x8 qf[2][2];
        for (int g = 0; g < 2; ++g) {
            const bf16_t* qp = qh + base + (size_t)(q0 + wl * 32 + g * 16 + l16) * 64;
            qf[g][0] = *(const bf16x8*)(qp + ((quad ^ swz) * 8));
            qf[g][1] = *(const bf16x8*)(qp + (((4 + quad) ^ swz) * 8));
        }

        f32x4 o[2][4];
        for (int g = 0; g < 2; ++g)
            for (int i = 0; i < 4; ++i) o[g][i] = (f32x4){0.f, 0.f, 0.f, 0.f};
        float lsum[2] = {0.f, 0.f};

        const int S  = qt2 + 1;             // total 128-key steps of this leg
        const int Sh = (S + 1) >> 1;        // z=0 takes [0,Sh), z=1 takes [Sh,S)
        const int it0 = z ? Sh : 0;
        const int it1 = z ? S : Sh;

        for (int it = it0; it < it1; ++it) {
            const int j0 = it * 128;
            __syncthreads();
            for (int j = 0; j < 2; ++j) {
                const int rk = wave * 16 + j * 8 + r8;      // 0..127
                async16(kh + base + (size_t)(j0 + rk) * 64 + c8,
                        KSM + (wave * 16 + j * 8) * 64);
                async16(vh + (size_t)(bh * 64 + (rk & 63)) * 4096 + j0 + (rk >> 6) * 64 + c8,
                        VSM + (wave * 16 + j * 8) * 64);
            }
            __syncthreads();

            const int pp = g2;
            const int koff = j0 + pp * 64 - q0;
            if (koff > wl * 32 + 31) continue;     // fully masked for this wave

            // S^T = K·Q^T (C: col=query=l16, row=key=nt*16+quad*4+r)
            f32x4 st[2][4];
            for (int nt = 0; nt < 4; ++nt) {
                const __bf16* kr = KSM + (pp * 64 + nt * 16 + l16) * 64;
                bf16x8 kf0 = *(const bf16x8*)(kr + ((quad ^ swz) * 8));
                bf16x8 kf1 = *(const bf16x8*)(kr + (((4 + quad) ^ swz) * 8));
                for (int g = 0; g < 2; ++g) {
                    f32x4 zz = (f32x4){0.f, 0.f, 0.f, 0.f};
                    zz = mfma_k32(kf0, qf[g][0], zz);
                    zz = mfma_k32(kf1, qf[g][1], zz);
                    st[g][nt] = zz;
                }
            }

            // fixed-base softmax: p = exp2(st)
            bf16x4 pf[2][4];
            for (int g = 0; g < 2; ++g) {
                const int qb = wl * 32 + g * 16;
                if (koff + 63 <= qb) {
                    for (int nt = 0; nt < 4; ++nt)
                        for (int r = 0; r < 4; ++r) {
                            float p = fast_exp2(st[g][nt][r]);
                            lsum[g] += p;
                            pf[g][nt][r] = (bf16_t)p;
                        }
                } else {
                    const int qrow = qb + l16;
                    for (int nt = 0; nt < 4; ++nt)
                        for (int r = 0; r < 4; ++r) {
                            int key = nt * 16 + quad * 4 + r;
                            float p = (key + koff <= qrow) ? fast_exp2(st[g][nt][r]) : 0.f;
                            lsum[g] += p;
                            pf[g][nt][r] = (bf16_t)p;
                        }
                }
            }

            // O += P·V (P register-resident)
            for (int dt = 0; dt < 4; ++dt)
                for (int kt2 = 0; kt2 < 2; ++kt2) {
                    bf16x8 vf = *(const bf16x8*)&VSM[(pp * 64 + dt * 16 + l16) * 64 + (((2 * quad + kt2) ^ swz) * 8)];
                    bf16x4 vlo = {vf[0], vf[1], vf[2], vf[3]};
                    bf16x4 vhi = {vf[4], vf[5], vf[6], vf[7]};
                    for (int g = 0; g < 2; ++g) {
                        o[g][dt] = mfma_k16(pf[g][2 * kt2], vlo, o[g][dt]);
                        o[g][dt] = mfma_k16(pf[g][2 * kt2 + 1], vhi, o[g][dt]);
                    }
                }
        }

        // ---- combine K-parity partials within block, write leg partials ----
        __syncthreads();                    // all K/V LDS reads done
        if (g2 == 1) {
            for (int g = 0; g < 2; ++g) {
                float ls = lsum[g];
                ls += __shfl_xor(ls, 16);
                ls += __shfl_xor(ls, 32);
                const int qb = wl * 32 + g * 16;
                Lsc[qb + l16] = ls;
                for (int dt = 0; dt < 4; ++dt)
                    for (int r = 0; r < 4; ++r)
                        Osc[(qb + quad * 4 + r) * 65 + dt * 16 + l16] = o[g][dt][r];
            }
        }
        __syncthreads();
        if (g2 == 0) {
            for (int g = 0; g < 2; ++g) {
                float ls = lsum[g];
                ls += __shfl_xor(ls, 16);
                ls += __shfl_xor(ls, 32);
                const int qb = wl * 32 + g * 16;
                ls += Lsc[qb + l16];
                Lsc[qb + l16] = ls;         // total lsum for this z
                for (int dt = 0; dt < 4; ++dt)
                    for (int r = 0; r < 4; ++r) {
                        int idx = (qb + quad * 4 + r) * 65 + dt * 16 + l16;
                        Osc[idx] = o[g][dt][r] + Osc[idx];
                    }
            }
        }
        __syncthreads();
        // repack: contiguous bf16 partial rows [q][e] + fp32 lsum
        {
            const int q  = tid >> 2;                    // 0..127
            const int e0 = (tid & 3) * 16;
            bf16x8 w0, w1;
            for (int i = 0; i < 8; ++i) {
                w0[i] = (bf16_t)Osc[q * 65 + e0 + i];
                w1[i] = (bf16_t)Osc[q * 65 + e0 + 8 + i];
            }
            size_t slot = ((size_t)bh * 4096 + q0 + q) * 64 + e0;
            *(bf16x8*)&Op[slot]     = w0;
            *(bf16x8*)&Op[slot + 8] = w1;
            if (tid < 128) Lp[bh * 4096 + q0 + tid] = Lsc[tid];
        }
        // next leg's first __syncthreads() protects Osc/Lsc reuse
    }
}

// ---------------------------------------------------------------------------
extern "C" void kernel_launch(void* const* d_in, const int* in_sizes, int n_in,
                              void* d_out, int out_size, void* d_ws, size_t ws_size,
                              hipStream_t stream) {
    const float* q  = (const float*)d_in[0];
    const float* k  = (const float*)d_in[1];
    const float* v  = (const float*)d_in[2];
    const float* Wq = (const float*)d_in[3];
    const float* Wk = (const float*)d_in[4];
    const float* Wv = (const float*)d_in[5];
    const float* Wo = (const float*)d_in[6];
    float* out = (float*)d_out;

    bf16_t* ws = (bf16_t*)d_ws;
    const size_t R = (size_t)8192 * 512;   // 4.19M elems = 8.39 MB per region
    bf16_t* opart = ws + R;          // R1+R2: Opart z0/z1
    bf16_t* vh = ws + 3 * R;         // R3: V^T heads
    bf16_t* Wc = ws + 4 * R;         // +2 MB bf16 weights (Wq pre-scaled)
    float*  Lp = (float*)(ws + 4 * R + 1048576);  // +0.5 MB lsum partials
    bf16_t* qh = (bf16_t*)d_out;     // qh/kh in d_out, dead before final GEMM
    bf16_t* kh = (bf16_t*)d_out + R;

    cvt_W<<<dim3(512), dim3(256), 0, stream>>>(Wq, Wk, Wv, Wo, Wc);
    proj_fused<<<dim3(256, 1, 3), dim3(256), 0, stream>>>(q, k, v, Wc, qh, kh, vh);
    attn_kernel<<<dim3(512), dim3(512), 0, stream>>>(qh, kh, vh, opart, Lp);
    gemm_final<<<dim3(256), dim3(256), 0, stream>>>(opart, Lp, Wc + 3 * 262144, out);
}